// Round 1
// baseline (322.905 us; speedup 1.0000x reference)
//
#include <hip/hip_runtime.h>
#include <math.h>

// KGAT attention aggregation, MI355X.
// fc1->fc2 with no activation collapses to one linear functional:
//   logit = concat . (W1@W2) + (b1.W2 + b2)
// The additive constant cancels in softmax over K, so the hot kernel only
// needs w = W1@W2 (384 floats).
//
// R4 (this round): persistent waves + depth-1 software pipeline.
//   Old kernel: one-shot waves, 36 VGPRs -> loads serialized into rounds of
//   issue/waitcnt/consume -> latency-bound at 1.7 TB/s HBM (21%).
//   New: each 32-lane half-wave owns a row stream (p += grid*8), double
//   buffers the 11 float4 loads (__launch_bounds__(256,4) -> ~120 VGPR
//   budget), issues next-row loads between the partial dots and the
//   butterfly so the shuffle/softmax/store tail hides HBM latency.
//   Also: entity dot folded into the 5 K-chains (30 -> 25 shuffles).

#define DIM 128
#define KN 5

typedef float nfloat4 __attribute__((ext_vector_type(4)));  // native vec for builtins

__device__ __forceinline__ float dot4(nfloat4 a, nfloat4 b) {
    return a.x * b.x + a.y * b.y + a.z * b.z + a.w * b.w;
}

// One wave per output element of w = W1@W2 (384 outputs) + one wave for c.
// (c = b1.W2 + b2 is still written for debugging but unused: softmax-invariant.)
__global__ __launch_bounds__(256) void kgat_prep(
    const float* __restrict__ W1,   // [384,128]
    const float* __restrict__ b1,   // [128]
    const float* __restrict__ W2,   // [128]
    const float* __restrict__ b2,   // [1]
    float* __restrict__ ws)         // w[384], c
{
    const int gw = blockIdx.x * 4 + (threadIdx.x >> 6);
    const int lane = threadIdx.x & 63;
    if (gw < 3 * DIM) {
        const int t = gw;
        const float2 w1 = *(const float2*)(W1 + (size_t)t * DIM + 2 * lane);
        const float2 w2 = *(const float2*)(W2 + 2 * lane);
        float v = w1.x * w2.x + w1.y * w2.y;
        #pragma unroll
        for (int off = 32; off >= 1; off >>= 1) v += __shfl_xor(v, off, 64);
        if (lane == 0) ws[t] = v;
    } else if (gw == 3 * DIM) {
        const float2 bb = *(const float2*)(b1 + 2 * lane);
        const float2 w2 = *(const float2*)(W2 + 2 * lane);
        float v = bb.x * w2.x + bb.y * w2.y;
        #pragma unroll
        for (int off = 32; off >= 1; off >>= 1) v += __shfl_xor(v, off, 64);
        if (lane == 0) ws[3 * DIM] = v + b2[0];
    }
}

// 32 lanes per (b,n) row; each wave handles 2 row-streams (half-waves
// independent); persistent grid-stride loop with one-row-ahead prefetch.
__global__ __launch_bounds__(256, 4) void kgat_main(
    const float* __restrict__ ent,   // [P, 128]
    const float* __restrict__ ne,    // [P, 5, 128]
    const float* __restrict__ nr,    // [P, 5, 128]
    const float* __restrict__ ws,    // w[384] (+c, unused)
    float* __restrict__ out,         // [P, 256]
    int P, int stride)               // stride = gridDim.x * 8 rows
{
    const int wave = threadIdx.x >> 6;
    const int lane = threadIdx.x & 63;
    const int half = lane >> 5;        // which row-stream within the wave
    const int l    = lane & 31;        // lane within the row
    const int d    = l * 4;

    int p = blockIdx.x * 8 + wave * 2 + half;
    if (p >= P) return;

    // broadcast weights (cache-resident, loop-invariant)
    const nfloat4 we  = *(const nfloat4*)(ws + d);
    const nfloat4 wne = *(const nfloat4*)(ws + DIM + d);
    const nfloat4 wnr = *(const nfloat4*)(ws + 2 * DIM + d);

    nfloat4 eA, neA[KN], nrA[KN];
    nfloat4 eB, neB[KN], nrB[KN];

    auto load_row = [&](int pp, nfloat4& e4, nfloat4 (&n4)[KN], nfloat4 (&r4)[KN]) {
        e4 = *(const nfloat4*)(ent + (size_t)pp * DIM + d);
        const size_t rowK = (size_t)pp * (KN * DIM) + d;
        #pragma unroll
        for (int k = 0; k < KN; ++k) {
            n4[k] = *(const nfloat4*)(ne + rowK + (size_t)k * DIM);
            r4[k] = *(const nfloat4*)(nr + rowK + (size_t)k * DIM);
        }
    };

    // Process row pc from buffer (e4,n4,r4); prefetch row pn into (en,nn,rn).
    auto process = [&](int pc, int pn,
                       nfloat4& e4, nfloat4 (&n4)[KN], nfloat4 (&r4)[KN],
                       nfloat4& en, nfloat4 (&nn)[KN], nfloat4 (&rn)[KN]) {
        // per-lane partial dots; entity dot folded into each K-chain
        float red[KN];
        const float ec = dot4(e4, we);
        #pragma unroll
        for (int k = 0; k < KN; ++k)
            red[k] = ec + dot4(n4[k], wne) + dot4(r4[k], wnr);

        // issue next row's loads now: their latency hides under the
        // butterfly (lgkm) + softmax (VALU) + stores below
        if (pn < P) load_row(pn, en, nn, rn);

        // 5-step butterfly within each 32-lane half (xor offsets < 32 stay in-half)
        #pragma unroll
        for (int j = 0; j < KN; ++j) {
            float v = red[j];
            #pragma unroll
            for (int off = 16; off >= 1; off >>= 1) v += __shfl_xor(v, off, 64);
            red[j] = v;
        }

        // softmax over K=5 (additive constant c cancels; redundant per lane)
        float m = red[0];
        #pragma unroll
        for (int k = 1; k < KN; ++k) m = fmaxf(m, red[k]);
        float ex[KN], s = 0.f;
        #pragma unroll
        for (int k = 0; k < KN; ++k) { ex[k] = __expf(red[k] - m); s += ex[k]; }
        const float inv = 1.f / s;

        // attention-weighted neighbor sum from registers (no re-read of ne)
        nfloat4 acc = {0.f, 0.f, 0.f, 0.f};
        #pragma unroll
        for (int k = 0; k < KN; ++k) {
            const float a = ex[k] * inv;
            acc.x += a * n4[k].x;
            acc.y += a * n4[k].y;
            acc.z += a * n4[k].z;
            acc.w += a * n4[k].w;
        }

        float* orow = out + (size_t)pc * (2 * DIM);
        __builtin_nontemporal_store(e4,  (nfloat4*)(orow + d));
        __builtin_nontemporal_store(acc, (nfloat4*)(orow + DIM + d));
    };

    load_row(p, eA, neA, nrA);
    for (;;) {
        int pn = p + stride;
        process(p, pn, eA, neA, nrA, eB, neB, nrB);
        p = pn;
        if (p >= P) break;
        pn = p + stride;
        process(p, pn, eB, neB, nrB, eA, neA, nrA);
        p = pn;
        if (p >= P) break;
    }
}

extern "C" void kernel_launch(void* const* d_in, const int* in_sizes, int n_in,
                              void* d_out, int out_size, void* d_ws, size_t ws_size,
                              hipStream_t stream) {
    const float* ent = (const float*)d_in[0];
    const float* ne  = (const float*)d_in[1];
    const float* nr  = (const float*)d_in[2];
    const float* W1  = (const float*)d_in[3];
    const float* b1  = (const float*)d_in[4];
    const float* W2  = (const float*)d_in[5];
    const float* b2  = (const float*)d_in[6];
    float* out = (float*)d_out;
    float* ws  = (float*)d_ws;

    const int P = in_sizes[0] / DIM;  // B*N rows

    kgat_prep<<<(3 * DIM + 1 + 3) / 4, 256, 0, stream>>>(W1, b1, W2, b2, ws);

    int nb = (P + 7) / 8;
    if (nb > 1024) nb = 1024;   // 256 CU x 4 resident blocks @ <=128 VGPR
    if (nb < 1) nb = 1;
    kgat_main<<<nb, 256, 0, stream>>>(ent, ne, nr, ws, out, P, nb * 8);
}